// Round 2
// baseline (1654.671 us; speedup 1.0000x reference)
//
#include <hip/hip_runtime.h>

#define HID 128

// ---------------- degree count ----------------
__global__ __launch_bounds__(256) void deg_kernel(const int* __restrict__ ei,
                                                  float* __restrict__ cnt, int E) {
    int e = blockIdx.x * 256 + threadIdx.x;
    if (e >= E) return;
    int dst = ei[E + e];
    atomicAdd(&cnt[dst], 1.0f);
}

// ---------------- layer-0 aggregation (11-dim) ----------------
__global__ __launch_bounds__(256) void agg0_kernel(const int* __restrict__ ei,
                                                   const float* __restrict__ x,
                                                   float* __restrict__ agg, int E) {
    long long g = (long long)blockIdx.x * 256 + threadIdx.x;
    int e = (int)(g >> 4);
    int lane = (int)(g & 15);
    if (e >= E || lane >= 11) return;
    int src = ei[e];
    int dst = ei[E + e];
    atomicAdd(&agg[(size_t)dst * 11 + lane], x[(size_t)src * 11 + lane]);
}

// ---------------- 128-dim aggregation: one wave per edge ----------------
__global__ __launch_bounds__(256) void agg128_kernel(const int* __restrict__ ei,
                                                     const float* __restrict__ h,
                                                     float* __restrict__ agg, int E) {
    long long g = (long long)blockIdx.x * 256 + threadIdx.x;
    int e = (int)(g >> 6);
    if (e >= E) return;
    int lane = threadIdx.x & 63;
    int src = ei[e];
    int dst = ei[E + e];
    float2 v = *(const float2*)(h + (size_t)src * HID + lane * 2);
    float* p = agg + (size_t)dst * HID + lane * 2;
    atomicAdd(p, v.x);
    atomicAdd(p + 1, v.y);
}

// ---------------- layer 0: K=11 dual matmul + LN + ReLU (wave per node) ----------------
__global__ __launch_bounds__(256) void layer0_kernel(
    const float* __restrict__ x, const float* __restrict__ agg, const float* __restrict__ cnt,
    const float* __restrict__ w_l, const float* __restrict__ b_l, const float* __restrict__ w_r,
    const float* __restrict__ ln_w, const float* __restrict__ ln_b,
    float* __restrict__ h_out, int n)
{
    int gw = (blockIdx.x * 256 + threadIdx.x) >> 6;  // node
    int lane = threadIdx.x & 63;
    if (gw >= n) return;
    float inv = 1.0f / fmaxf(cnt[gw], 1.0f);
    float v0 = b_l[lane], v1 = b_l[lane + 64];
    #pragma unroll
    for (int k = 0; k < 11; ++k) {
        float a  = agg[(size_t)gw * 11 + k] * inv;
        float xi = x[(size_t)gw * 11 + k];
        v0 += a * w_l[k * HID + lane]      + xi * w_r[k * HID + lane];
        v1 += a * w_l[k * HID + lane + 64] + xi * w_r[k * HID + lane + 64];
    }
    float s = v0 + v1, s2 = v0 * v0 + v1 * v1;
    #pragma unroll
    for (int m = 1; m < 64; m <<= 1) { s += __shfl_xor(s, m); s2 += __shfl_xor(s2, m); }
    float mu  = s * (1.0f / HID);
    float var = s2 * (1.0f / HID) - mu * mu;
    float rstd = rsqrtf(var + 1e-5f);
    float o0 = fmaxf((v0 - mu) * rstd * ln_w[lane]      + ln_b[lane],      0.0f);
    float o1 = fmaxf((v1 - mu) * rstd * ln_w[lane + 64] + ln_b[lane + 64], 0.0f);
    h_out[(size_t)gw * HID + lane]      = o0;
    h_out[(size_t)gw * HID + lane + 64] = o1;
}

// ---------------- layers 1/2: [64 nodes] x (agg|h_in)[256] @ W[256][128] + LN + ReLU + res ----
// NOTE: h_out may alias agg — each block reads only its own 64 rows of agg/h_in
// (fully staged to LDS before __syncthreads), then writes only those same rows.
template<int RES>
__global__ __launch_bounds__(256) void layer_kernel(
    const float* __restrict__ agg, const float* __restrict__ cnt, const float* __restrict__ h_in,
    const float* __restrict__ w_l, const float* __restrict__ b_l, const float* __restrict__ w_r,
    const float* __restrict__ ln_w, const float* __restrict__ ln_b,
    float* __restrict__ h_out, int n)
{
    __shared__ float lds[64][260];   // [node][agg(128) | h_in(128)], stride 260 (pad)
    int base = blockIdx.x * 64;
    int tid = threadIdx.x;
    // stage: 64 rows x 2x128 cols, float4 per thread-iter
    #pragma unroll
    for (int i = 0; i < 8; ++i) {
        int idx = tid + i * 256;            // float4 index over 64*128/4 = 2048
        int row = idx >> 5;
        int c4  = (idx & 31) * 4;
        int node = base + row;
        float4 a = make_float4(0.f, 0.f, 0.f, 0.f);
        float4 h = make_float4(0.f, 0.f, 0.f, 0.f);
        if (node < n) {
            a = *(const float4*)(agg + (size_t)node * HID + c4);
            float inv = 1.0f / fmaxf(cnt[node], 1.0f);
            a.x *= inv; a.y *= inv; a.z *= inv; a.w *= inv;
            h = *(const float4*)(h_in + (size_t)node * HID + c4);
        }
        *(float4*)&lds[row][c4]       = a;
        *(float4*)&lds[row][HID + c4] = h;
    }
    __syncthreads();

    int tx = tid & 31, ty = tid >> 5;   // tx: 32 col-groups (4 cols each), ty: 8 row-groups (8 rows each)
    float acc[8][4];
    #pragma unroll
    for (int r = 0; r < 8; ++r) { acc[r][0] = acc[r][1] = acc[r][2] = acc[r][3] = 0.f; }

    const float* W = w_l;
    #pragma unroll
    for (int half = 0; half < 2; ++half) {
        int koff = half * HID;
        for (int k = 0; k < HID; k += 4) {
            float4 w0 = *(const float4*)(W + (size_t)(k + 0) * HID + tx * 4);
            float4 w1 = *(const float4*)(W + (size_t)(k + 1) * HID + tx * 4);
            float4 w2 = *(const float4*)(W + (size_t)(k + 2) * HID + tx * 4);
            float4 w3 = *(const float4*)(W + (size_t)(k + 3) * HID + tx * 4);
            #pragma unroll
            for (int r = 0; r < 8; ++r) {
                float4 a = *(const float4*)&lds[ty * 8 + r][koff + k];
                acc[r][0] = fmaf(a.x, w0.x, fmaf(a.y, w1.x, fmaf(a.z, w2.x, fmaf(a.w, w3.x, acc[r][0]))));
                acc[r][1] = fmaf(a.x, w0.y, fmaf(a.y, w1.y, fmaf(a.z, w2.y, fmaf(a.w, w3.y, acc[r][1]))));
                acc[r][2] = fmaf(a.x, w0.z, fmaf(a.y, w1.z, fmaf(a.z, w2.z, fmaf(a.w, w3.z, acc[r][2]))));
                acc[r][3] = fmaf(a.x, w0.w, fmaf(a.y, w1.w, fmaf(a.z, w2.w, fmaf(a.w, w3.w, acc[r][3]))));
            }
        }
        W = w_r;
    }

    float4 bl = *(const float4*)(b_l  + tx * 4);
    float4 gw = *(const float4*)(ln_w + tx * 4);
    float4 gb = *(const float4*)(ln_b + tx * 4);
    #pragma unroll
    for (int r = 0; r < 8; ++r) {
        float v0 = acc[r][0] + bl.x, v1 = acc[r][1] + bl.y;
        float v2 = acc[r][2] + bl.z, v3 = acc[r][3] + bl.w;
        float s  = v0 + v1 + v2 + v3;
        float s2 = v0*v0 + v1*v1 + v2*v2 + v3*v3;
        #pragma unroll
        for (int m = 16; m >= 1; m >>= 1) { s += __shfl_xor(s, m); s2 += __shfl_xor(s2, m); }
        float mu  = s * (1.0f / HID);
        float var = s2 * (1.0f / HID) - mu * mu;
        float rstd = rsqrtf(var + 1e-5f);
        int row = ty * 8 + r;
        float o0 = fmaxf((v0 - mu) * rstd * gw.x + gb.x, 0.f);
        float o1 = fmaxf((v1 - mu) * rstd * gw.y + gb.y, 0.f);
        float o2 = fmaxf((v2 - mu) * rstd * gw.z + gb.z, 0.f);
        float o3 = fmaxf((v3 - mu) * rstd * gw.w + gb.w, 0.f);
        if (RES) {
            o0 += lds[row][HID + tx * 4 + 0];
            o1 += lds[row][HID + tx * 4 + 1];
            o2 += lds[row][HID + tx * 4 + 2];
            o3 += lds[row][HID + tx * 4 + 3];
        }
        int node = base + row;
        if (node < n) {
            float4 o = make_float4(o0, o1, o2, o3);
            *(float4*)(h_out + (size_t)node * HID + tx * 4) = o;
        }
    }
}

// ---------------- classifier: relu(h@c_w0+b0)@c_w1+b1, wave per node ----------------
__global__ __launch_bounds__(256) void cls_kernel(
    const float* __restrict__ h, const float* __restrict__ w0, const float* __restrict__ b0,
    const float* __restrict__ w1, const float* __restrict__ b1, float* __restrict__ out, int n)
{
    __shared__ float w0s[HID * 64];
    __shared__ float w1s[64];
    int tid = threadIdx.x;
    #pragma unroll
    for (int i = 0; i < 32; ++i) w0s[tid + i * 256] = w0[tid + i * 256];
    if (tid < 64) w1s[tid] = w1[tid];
    __syncthreads();
    int lane = tid & 63, wv = tid >> 6;
    float bb0 = b0[lane], bb1 = b1[0];
    for (int i = 0; i < 16; ++i) {
        int node = blockIdx.x * 64 + wv * 16 + i;
        if (node >= n) break;
        const float* hr = h + (size_t)node * HID;
        float s = bb0;
        #pragma unroll 4
        for (int k = 0; k < HID; k += 4) {
            float4 hv = *(const float4*)(hr + k);
            s = fmaf(hv.x, w0s[(k + 0) * 64 + lane], s);
            s = fmaf(hv.y, w0s[(k + 1) * 64 + lane], s);
            s = fmaf(hv.z, w0s[(k + 2) * 64 + lane], s);
            s = fmaf(hv.w, w0s[(k + 3) * 64 + lane], s);
        }
        s = fmaxf(s, 0.f);
        float t = s * w1s[lane];
        #pragma unroll
        for (int m = 1; m < 64; m <<= 1) t += __shfl_xor(t, m);
        if (lane == 0) out[node] = t + bb1;
    }
}

extern "C" void kernel_launch(void* const* d_in, const int* in_sizes, int n_in,
                              void* d_out, int out_size, void* d_ws, size_t ws_size,
                              hipStream_t stream) {
    const float* x  = (const float*)d_in[0];
    const int*   ei = (const int*)d_in[1];     // harness delivers integer inputs as int32
    const float* w_l0 = (const float*)d_in[2];
    const float* b_l0 = (const float*)d_in[3];
    const float* w_r0 = (const float*)d_in[4];
    const float* lnw0 = (const float*)d_in[5];
    const float* lnb0 = (const float*)d_in[6];
    const float* w_l1 = (const float*)d_in[7];
    const float* b_l1 = (const float*)d_in[8];
    const float* w_r1 = (const float*)d_in[9];
    const float* lnw1 = (const float*)d_in[10];
    const float* lnb1 = (const float*)d_in[11];
    const float* w_l2 = (const float*)d_in[12];
    const float* b_l2 = (const float*)d_in[13];
    const float* w_r2 = (const float*)d_in[14];
    const float* lnw2 = (const float*)d_in[15];
    const float* lnb2 = (const float*)d_in[16];
    const float* c_w0 = (const float*)d_in[17];
    const float* c_b0 = (const float*)d_in[18];
    const float* c_w1 = (const float*)d_in[19];
    const float* c_b1 = (const float*)d_in[20];
    float* out = (float*)d_out;

    int N = in_sizes[0] / 11;
    int E = in_sizes[1] / 2;

    // workspace layout (floats): [cnt: Npad][aggS: N*11][bufA: N*HID][bufB: N*HID]
    float* ws = (float*)d_ws;
    size_t Npad = ((size_t)(N + 255) / 256) * 256;
    float* cnt  = ws;
    float* aggS = ws + Npad;
    float* bufA = aggS + (size_t)N * 11;
    float* bufB = bufA + (size_t)N * HID;

    // degrees (shared by all layers)
    hipMemsetAsync(cnt, 0, Npad * sizeof(float), stream);
    deg_kernel<<<(E + 255) / 256, 256, 0, stream>>>(ei, cnt, E);

    // ---- layer 0 ----
    hipMemsetAsync(aggS, 0, (size_t)N * 11 * sizeof(float), stream);
    agg0_kernel<<<(int)(((long long)E * 16 + 255) / 256), 256, 0, stream>>>(ei, x, aggS, E);
    layer0_kernel<<<(N + 3) / 4, 256, 0, stream>>>(x, aggS, cnt, w_l0, b_l0, w_r0, lnw0, lnb0, bufA, N);

    // ---- layer 1 ----  (h_out aliases agg buffer bufB)
    hipMemsetAsync(bufB, 0, (size_t)N * HID * sizeof(float), stream);
    agg128_kernel<<<(int)(((long long)E * 64 + 255) / 256), 256, 0, stream>>>(ei, bufA, bufB, E);
    layer_kernel<1><<<(N + 63) / 64, 256, 0, stream>>>(bufB, cnt, bufA, w_l1, b_l1, w_r1, lnw1, lnb1, bufB, N);

    // ---- layer 2 ----  (h_out aliases agg buffer bufA)
    hipMemsetAsync(bufA, 0, (size_t)N * HID * sizeof(float), stream);
    agg128_kernel<<<(int)(((long long)E * 64 + 255) / 256), 256, 0, stream>>>(ei, bufB, bufA, E);
    layer_kernel<1><<<(N + 63) / 64, 256, 0, stream>>>(bufA, cnt, bufB, w_l2, b_l2, w_r2, lnw2, lnb2, bufA, N);

    // ---- classifier ----
    cls_kernel<<<(N + 63) / 64, 256, 0, stream>>>(bufA, c_w0, c_b0, c_w1, c_b1, out, N);
}

// Round 3
// 622.454 us; speedup vs baseline: 2.6583x; 2.6583x over previous
//
#include <hip/hip_runtime.h>

#define HID 128

// ---------------- degree histogram (int) ----------------
__global__ __launch_bounds__(256) void deg_kernel(const int* __restrict__ ei,
                                                  int* __restrict__ deg, int E) {
    int e = blockIdx.x * 256 + threadIdx.x;
    if (e >= E) return;
    atomicAdd(&deg[ei[E + e]], 1);
}

// ---------------- exclusive scan of deg -> row_ptr, cursor (single block) ----------------
__global__ __launch_bounds__(1024) void scan_kernel(const int* __restrict__ deg,
                                                    int* __restrict__ rp,
                                                    int* __restrict__ cursor, int n) {
    __shared__ int part[1024];
    int t = threadIdx.x;
    int chunk = (n + 1023) / 1024;
    int b = t * chunk;
    int e = b + chunk; if (e > n) e = n; if (b > n) b = n;
    int s = 0;
    for (int i = b; i < e; ++i) s += deg[i];
    part[t] = s;
    __syncthreads();
    for (int off = 1; off < 1024; off <<= 1) {
        int v = (t >= off) ? part[t - off] : 0;
        __syncthreads();
        part[t] += v;
        __syncthreads();
    }
    int run = part[t] - s;   // exclusive base for this chunk
    for (int i = b; i < e; ++i) {
        rp[i] = run; cursor[i] = run;
        run += deg[i];
    }
    if (e == n) rp[n] = run;   // all such threads write the same total E
}

// ---------------- CSR fill ----------------
__global__ __launch_bounds__(256) void fill_kernel(const int* __restrict__ ei,
                                                   int* __restrict__ cursor,
                                                   int* __restrict__ csr_src, int E) {
    int e = blockIdx.x * 256 + threadIdx.x;
    if (e >= E) return;
    int dst = ei[E + e];
    int pos = atomicAdd(&cursor[dst], 1);
    csr_src[pos] = ei[e];
}

// ---------------- 128-dim pull aggregation: one wave per node, writes MEAN ----------------
__global__ __launch_bounds__(256) void aggp_kernel(const int* __restrict__ rp,
                                                   const int* __restrict__ ci,
                                                   const float* __restrict__ h,
                                                   float* __restrict__ agg, int n) {
    int node = (blockIdx.x * 256 + threadIdx.x) >> 6;
    if (node >= n) return;
    int lane = threadIdx.x & 63;
    int beg = rp[node], end = rp[node + 1];
    float2 a0 = make_float2(0.f, 0.f), a1 = make_float2(0.f, 0.f);
    int j = beg;
    for (; j + 1 < end; j += 2) {
        int s0 = ci[j], s1 = ci[j + 1];
        float2 v0 = *(const float2*)(h + (size_t)s0 * HID + lane * 2);
        float2 v1 = *(const float2*)(h + (size_t)s1 * HID + lane * 2);
        a0.x += v0.x; a0.y += v0.y;
        a1.x += v1.x; a1.y += v1.y;
    }
    if (j < end) {
        int s0 = ci[j];
        float2 v0 = *(const float2*)(h + (size_t)s0 * HID + lane * 2);
        a0.x += v0.x; a0.y += v0.y;
    }
    float inv = 1.0f / fmaxf((float)(end - beg), 1.0f);
    float2 o = make_float2((a0.x + a1.x) * inv, (a0.y + a1.y) * inv);
    *(float2*)(agg + (size_t)node * HID + lane * 2) = o;
}

// ---------------- layer 0: fused 11-dim pull-agg + dual matmul + LN + ReLU ----------------
__global__ __launch_bounds__(256) void layer0_kernel(
    const float* __restrict__ x, const int* __restrict__ rp, const int* __restrict__ ci,
    const float* __restrict__ w_l, const float* __restrict__ b_l, const float* __restrict__ w_r,
    const float* __restrict__ ln_w, const float* __restrict__ ln_b,
    float* __restrict__ h_out, int n)
{
    int node = (blockIdx.x * 256 + threadIdx.x) >> 6;
    int lane = threadIdx.x & 63;
    if (node >= n) return;
    int beg = rp[node], end = rp[node + 1];
    float aggk = 0.f;
    for (int j = beg; j < end; ++j) {
        int src = ci[j];
        if (lane < 11) aggk += x[(size_t)src * 11 + lane];
    }
    float inv = 1.0f / fmaxf((float)(end - beg), 1.0f);
    float v0 = b_l[lane], v1 = b_l[lane + 64];
    #pragma unroll
    for (int k = 0; k < 11; ++k) {
        float a  = __shfl(aggk, k) * inv;
        float xi = x[(size_t)node * 11 + k];
        v0 += a * w_l[k * HID + lane]      + xi * w_r[k * HID + lane];
        v1 += a * w_l[k * HID + lane + 64] + xi * w_r[k * HID + lane + 64];
    }
    float s = v0 + v1, s2 = v0 * v0 + v1 * v1;
    #pragma unroll
    for (int m = 1; m < 64; m <<= 1) { s += __shfl_xor(s, m); s2 += __shfl_xor(s2, m); }
    float mu  = s * (1.0f / HID);
    float var = s2 * (1.0f / HID) - mu * mu;
    float rstd = rsqrtf(var + 1e-5f);
    float o0 = fmaxf((v0 - mu) * rstd * ln_w[lane]      + ln_b[lane],      0.0f);
    float o1 = fmaxf((v1 - mu) * rstd * ln_w[lane + 64] + ln_b[lane + 64], 0.0f);
    h_out[(size_t)node * HID + lane]      = o0;
    h_out[(size_t)node * HID + lane + 64] = o1;
}

// ---------------- layers 1/2: [64 nodes] x (agg|h_in)[256] @ W[256][128] + LN + ReLU + res ----
// h_out may alias agg or h_in: each block stages its own 64 rows to LDS before writing.
template<int RES>
__global__ __launch_bounds__(256) void layer_kernel(
    const float* __restrict__ agg, const float* __restrict__ h_in,
    const float* __restrict__ w_l, const float* __restrict__ b_l, const float* __restrict__ w_r,
    const float* __restrict__ ln_w, const float* __restrict__ ln_b,
    float* __restrict__ h_out, int n)
{
    __shared__ float lds[64][260];   // [node][agg(128) | h_in(128)]
    int base = blockIdx.x * 64;
    int tid = threadIdx.x;
    #pragma unroll
    for (int i = 0; i < 8; ++i) {
        int idx = tid + i * 256;
        int row = idx >> 5;
        int c4  = (idx & 31) * 4;
        int node = base + row;
        float4 a = make_float4(0.f, 0.f, 0.f, 0.f);
        float4 h = make_float4(0.f, 0.f, 0.f, 0.f);
        if (node < n) {
            a = *(const float4*)(agg  + (size_t)node * HID + c4);
            h = *(const float4*)(h_in + (size_t)node * HID + c4);
        }
        *(float4*)&lds[row][c4]       = a;
        *(float4*)&lds[row][HID + c4] = h;
    }
    __syncthreads();

    int tx = tid & 31, ty = tid >> 5;
    float acc[8][4];
    #pragma unroll
    for (int r = 0; r < 8; ++r) { acc[r][0] = acc[r][1] = acc[r][2] = acc[r][3] = 0.f; }

    const float* W = w_l;
    #pragma unroll
    for (int half = 0; half < 2; ++half) {
        int koff = half * HID;
        for (int k = 0; k < HID; k += 4) {
            float4 w0 = *(const float4*)(W + (size_t)(k + 0) * HID + tx * 4);
            float4 w1 = *(const float4*)(W + (size_t)(k + 1) * HID + tx * 4);
            float4 w2 = *(const float4*)(W + (size_t)(k + 2) * HID + tx * 4);
            float4 w3 = *(const float4*)(W + (size_t)(k + 3) * HID + tx * 4);
            #pragma unroll
            for (int r = 0; r < 8; ++r) {
                float4 a = *(const float4*)&lds[ty * 8 + r][koff + k];
                acc[r][0] = fmaf(a.x, w0.x, fmaf(a.y, w1.x, fmaf(a.z, w2.x, fmaf(a.w, w3.x, acc[r][0]))));
                acc[r][1] = fmaf(a.x, w0.y, fmaf(a.y, w1.y, fmaf(a.z, w2.y, fmaf(a.w, w3.y, acc[r][1]))));
                acc[r][2] = fmaf(a.x, w0.z, fmaf(a.y, w1.z, fmaf(a.z, w2.z, fmaf(a.w, w3.z, acc[r][2]))));
                acc[r][3] = fmaf(a.x, w0.w, fmaf(a.y, w1.w, fmaf(a.z, w2.w, fmaf(a.w, w3.w, acc[r][3]))));
            }
        }
        W = w_r;
    }

    float4 bl = *(const float4*)(b_l  + tx * 4);
    float4 gw = *(const float4*)(ln_w + tx * 4);
    float4 gb = *(const float4*)(ln_b + tx * 4);
    #pragma unroll
    for (int r = 0; r < 8; ++r) {
        float v0 = acc[r][0] + bl.x, v1 = acc[r][1] + bl.y;
        float v2 = acc[r][2] + bl.z, v3 = acc[r][3] + bl.w;
        float s  = v0 + v1 + v2 + v3;
        float s2 = v0*v0 + v1*v1 + v2*v2 + v3*v3;
        #pragma unroll
        for (int m = 16; m >= 1; m >>= 1) { s += __shfl_xor(s, m); s2 += __shfl_xor(s2, m); }
        float mu  = s * (1.0f / HID);
        float var = s2 * (1.0f / HID) - mu * mu;
        float rstd = rsqrtf(var + 1e-5f);
        int row = ty * 8 + r;
        float o0 = fmaxf((v0 - mu) * rstd * gw.x + gb.x, 0.f);
        float o1 = fmaxf((v1 - mu) * rstd * gw.y + gb.y, 0.f);
        float o2 = fmaxf((v2 - mu) * rstd * gw.z + gb.z, 0.f);
        float o3 = fmaxf((v3 - mu) * rstd * gw.w + gb.w, 0.f);
        if (RES) {
            o0 += lds[row][HID + tx * 4 + 0];
            o1 += lds[row][HID + tx * 4 + 1];
            o2 += lds[row][HID + tx * 4 + 2];
            o3 += lds[row][HID + tx * 4 + 3];
        }
        int node = base + row;
        if (node < n) {
            float4 o = make_float4(o0, o1, o2, o3);
            *(float4*)(h_out + (size_t)node * HID + tx * 4) = o;
        }
    }
}

// ---------------- classifier ----------------
__global__ __launch_bounds__(256) void cls_kernel(
    const float* __restrict__ h, const float* __restrict__ w0, const float* __restrict__ b0,
    const float* __restrict__ w1, const float* __restrict__ b1, float* __restrict__ out, int n)
{
    __shared__ float w0s[HID * 64];
    __shared__ float w1s[64];
    int tid = threadIdx.x;
    #pragma unroll
    for (int i = 0; i < 32; ++i) w0s[tid + i * 256] = w0[tid + i * 256];
    if (tid < 64) w1s[tid] = w1[tid];
    __syncthreads();
    int lane = tid & 63, wv = tid >> 6;
    float bb0 = b0[lane], bb1 = b1[0];
    for (int i = 0; i < 16; ++i) {
        int node = blockIdx.x * 64 + wv * 16 + i;
        if (node >= n) break;
        const float* hr = h + (size_t)node * HID;
        float s = bb0;
        #pragma unroll 4
        for (int k = 0; k < HID; k += 4) {
            float4 hv = *(const float4*)(hr + k);
            s = fmaf(hv.x, w0s[(k + 0) * 64 + lane], s);
            s = fmaf(hv.y, w0s[(k + 1) * 64 + lane], s);
            s = fmaf(hv.z, w0s[(k + 2) * 64 + lane], s);
            s = fmaf(hv.w, w0s[(k + 3) * 64 + lane], s);
        }
        s = fmaxf(s, 0.f);
        float t = s * w1s[lane];
        #pragma unroll
        for (int m = 1; m < 64; m <<= 1) t += __shfl_xor(t, m);
        if (lane == 0) out[node] = t + bb1;
    }
}

extern "C" void kernel_launch(void* const* d_in, const int* in_sizes, int n_in,
                              void* d_out, int out_size, void* d_ws, size_t ws_size,
                              hipStream_t stream) {
    const float* x  = (const float*)d_in[0];
    const int*   ei = (const int*)d_in[1];     // integer inputs arrive as int32
    const float* w_l0 = (const float*)d_in[2];
    const float* b_l0 = (const float*)d_in[3];
    const float* w_r0 = (const float*)d_in[4];
    const float* lnw0 = (const float*)d_in[5];
    const float* lnb0 = (const float*)d_in[6];
    const float* w_l1 = (const float*)d_in[7];
    const float* b_l1 = (const float*)d_in[8];
    const float* w_r1 = (const float*)d_in[9];
    const float* lnw1 = (const float*)d_in[10];
    const float* lnb1 = (const float*)d_in[11];
    const float* w_l2 = (const float*)d_in[12];
    const float* b_l2 = (const float*)d_in[13];
    const float* w_r2 = (const float*)d_in[14];
    const float* lnw2 = (const float*)d_in[15];
    const float* lnb2 = (const float*)d_in[16];
    const float* c_w0 = (const float*)d_in[17];
    const float* c_b0 = (const float*)d_in[18];
    const float* c_w1 = (const float*)d_in[19];
    const float* c_b1 = (const float*)d_in[20];
    float* out = (float*)d_out;

    int N = in_sizes[0] / 11;
    int E = in_sizes[1] / 2;

    // workspace (ints then floats):
    // [deg: N][rp: N+1][cursor: N][csr_src: E]  [bufA: N*HID][bufB: N*HID]
    int*   deg    = (int*)d_ws;
    int*   rp     = deg + N;
    int*   cursor = rp + (N + 1);
    int*   csr    = cursor + N;
    float* bufA   = (float*)(csr + E);
    float* bufB   = bufA + (size_t)N * HID;

    // ---- CSR build (once, reused by all 3 layers) ----
    hipMemsetAsync(deg, 0, (size_t)N * sizeof(int), stream);
    deg_kernel<<<(E + 255) / 256, 256, 0, stream>>>(ei, deg, E);
    scan_kernel<<<1, 1024, 0, stream>>>(deg, rp, cursor, N);
    fill_kernel<<<(E + 255) / 256, 256, 0, stream>>>(ei, cursor, csr, E);

    int nodeBlocks = (N + 3) / 4;   // 4 waves of work per 256-thread block

    // ---- layer 0 ----  h0 -> bufA
    layer0_kernel<<<nodeBlocks, 256, 0, stream>>>(x, rp, csr, w_l0, b_l0, w_r0, lnw0, lnb0, bufA, N);

    // ---- layer 1 ----  agg(bufA)->bufB ; layer(bufB, bufA) -> bufA (aliases h_in, LDS-staged)
    aggp_kernel<<<nodeBlocks, 256, 0, stream>>>(rp, csr, bufA, bufB, N);
    layer_kernel<1><<<(N + 63) / 64, 256, 0, stream>>>(bufB, bufA, w_l1, b_l1, w_r1, lnw1, lnb1, bufA, N);

    // ---- layer 2 ----  agg(bufA)->bufB ; layer(bufB, bufA) -> bufA
    aggp_kernel<<<nodeBlocks, 256, 0, stream>>>(rp, csr, bufA, bufB, N);
    layer_kernel<1><<<(N + 63) / 64, 256, 0, stream>>>(bufB, bufA, w_l2, b_l2, w_r2, lnw2, lnb2, bufA, N);

    // ---- classifier ----
    cls_kernel<<<(N + 63) / 64, 256, 0, stream>>>(bufA, c_w0, c_b0, c_w1, c_b1, out, N);
}

// Round 4
// 466.973 us; speedup vs baseline: 3.5434x; 1.3330x over previous
//
#include <hip/hip_runtime.h>

#define HID 128

// ---------------- degree histogram (int) ----------------
__global__ __launch_bounds__(256) void deg_kernel(const int* __restrict__ ei,
                                                  int* __restrict__ deg, int E) {
    int e = blockIdx.x * 256 + threadIdx.x;
    if (e >= E) return;
    atomicAdd(&deg[ei[E + e]], 1);
}

// ---------------- scan stage 1: per-block (256 elems) sums ----------------
__global__ __launch_bounds__(256) void part_kernel(const int* __restrict__ deg,
                                                   int* __restrict__ part, int n) {
    int i = blockIdx.x * 256 + threadIdx.x;
    int v = (i < n) ? deg[i] : 0;
    #pragma unroll
    for (int m = 1; m < 64; m <<= 1) v += __shfl_xor(v, m);
    __shared__ int w[4];
    int lane = threadIdx.x & 63, wv = threadIdx.x >> 6;
    if (lane == 0) w[wv] = v;
    __syncthreads();
    if (threadIdx.x == 0) part[blockIdx.x] = w[0] + w[1] + w[2] + w[3];
}

// ---------------- scan stage 2: exclusive scan of block sums (1 small block) ----------------
__global__ __launch_bounds__(1024) void scanpart_kernel(int* __restrict__ part, int nb) {
    __shared__ int s[1024];
    int t = threadIdx.x;
    int v = (t < nb) ? part[t] : 0;
    int orig = v;
    s[t] = v;
    __syncthreads();
    for (int off = 1; off < 1024; off <<= 1) {
        int u = (t >= off) ? s[t - off] : 0;
        __syncthreads();
        s[t] += u;
        __syncthreads();
    }
    if (t < nb) part[t] = s[t] - orig;   // exclusive
}

// ---------------- scan stage 3: per-block exclusive scan -> rp, cursor ----------------
__global__ __launch_bounds__(256) void rp_kernel(const int* __restrict__ deg,
                                                 const int* __restrict__ part,
                                                 int* __restrict__ rp,
                                                 int* __restrict__ cursor, int n) {
    int tid = threadIdx.x, lane = tid & 63, wv = tid >> 6;
    int i = blockIdx.x * 256 + tid;
    int v = (i < n) ? deg[i] : 0;
    int orig = v;
    #pragma unroll
    for (int off = 1; off < 64; off <<= 1) {
        int t = __shfl_up(v, off);
        if (lane >= off) v += t;
    }
    __shared__ int wsum[4];
    if (lane == 63) wsum[wv] = v;
    __syncthreads();
    int wbase = 0;
    #pragma unroll
    for (int w = 0; w < 4; ++w) if (w < wv) wbase += wsum[w];
    int excl = part[blockIdx.x] + wbase + v - orig;
    if (i < n) { rp[i] = excl; cursor[i] = excl; }
    if (i == n - 1) rp[n] = excl + orig;
}

// ---------------- CSR fill ----------------
__global__ __launch_bounds__(256) void fill_kernel(const int* __restrict__ ei,
                                                   int* __restrict__ cursor,
                                                   int* __restrict__ csr_src, int E) {
    int e = blockIdx.x * 256 + threadIdx.x;
    if (e >= E) return;
    int dst = ei[E + e];
    int pos = atomicAdd(&cursor[dst], 1);
    csr_src[pos] = ei[e];
}

// ---------------- 128-dim pull aggregation: one wave per node, writes MEAN ----------------
__global__ __launch_bounds__(256) void aggp_kernel(const int* __restrict__ rp,
                                                   const int* __restrict__ ci,
                                                   const float* __restrict__ h,
                                                   float* __restrict__ agg, int n) {
    int node = (blockIdx.x * 256 + threadIdx.x) >> 6;
    if (node >= n) return;
    int lane = threadIdx.x & 63;
    int beg = rp[node], end = rp[node + 1];
    float2 a0 = make_float2(0.f, 0.f), a1 = make_float2(0.f, 0.f);
    float2 a2 = make_float2(0.f, 0.f), a3 = make_float2(0.f, 0.f);
    int j = beg;
    for (; j + 3 < end; j += 4) {
        int s0 = ci[j], s1 = ci[j + 1], s2 = ci[j + 2], s3 = ci[j + 3];
        float2 v0 = *(const float2*)(h + (size_t)s0 * HID + lane * 2);
        float2 v1 = *(const float2*)(h + (size_t)s1 * HID + lane * 2);
        float2 v2 = *(const float2*)(h + (size_t)s2 * HID + lane * 2);
        float2 v3 = *(const float2*)(h + (size_t)s3 * HID + lane * 2);
        a0.x += v0.x; a0.y += v0.y;
        a1.x += v1.x; a1.y += v1.y;
        a2.x += v2.x; a2.y += v2.y;
        a3.x += v3.x; a3.y += v3.y;
    }
    for (; j < end; ++j) {
        int s0 = ci[j];
        float2 v0 = *(const float2*)(h + (size_t)s0 * HID + lane * 2);
        a0.x += v0.x; a0.y += v0.y;
    }
    float inv = 1.0f / fmaxf((float)(end - beg), 1.0f);
    float2 o = make_float2((a0.x + a1.x + a2.x + a3.x) * inv,
                           (a0.y + a1.y + a2.y + a3.y) * inv);
    *(float2*)(agg + (size_t)node * HID + lane * 2) = o;
}

// ---------------- layer 0: fused 11-dim pull-agg + dual matmul + LN + ReLU ----------------
__global__ __launch_bounds__(256) void layer0_kernel(
    const float* __restrict__ x, const int* __restrict__ rp, const int* __restrict__ ci,
    const float* __restrict__ w_l, const float* __restrict__ b_l, const float* __restrict__ w_r,
    const float* __restrict__ ln_w, const float* __restrict__ ln_b,
    float* __restrict__ h_out, int n)
{
    int node = (blockIdx.x * 256 + threadIdx.x) >> 6;
    int lane = threadIdx.x & 63;
    if (node >= n) return;
    int beg = rp[node], end = rp[node + 1];
    float g0 = 0.f, g1 = 0.f, g2 = 0.f, g3 = 0.f;
    int j = beg;
    for (; j + 3 < end; j += 4) {
        int s0 = ci[j], s1 = ci[j + 1], s2 = ci[j + 2], s3 = ci[j + 3];
        if (lane < 11) {
            g0 += x[(size_t)s0 * 11 + lane];
            g1 += x[(size_t)s1 * 11 + lane];
            g2 += x[(size_t)s2 * 11 + lane];
            g3 += x[(size_t)s3 * 11 + lane];
        }
    }
    for (; j < end; ++j) {
        int s0 = ci[j];
        if (lane < 11) g0 += x[(size_t)s0 * 11 + lane];
    }
    float aggk = g0 + g1 + g2 + g3;
    float inv = 1.0f / fmaxf((float)(end - beg), 1.0f);
    float v0 = b_l[lane], v1 = b_l[lane + 64];
    #pragma unroll
    for (int k = 0; k < 11; ++k) {
        float a  = __shfl(aggk, k) * inv;
        float xi = x[(size_t)node * 11 + k];
        v0 += a * w_l[k * HID + lane]      + xi * w_r[k * HID + lane];
        v1 += a * w_l[k * HID + lane + 64] + xi * w_r[k * HID + lane + 64];
    }
    float s = v0 + v1, s2 = v0 * v0 + v1 * v1;
    #pragma unroll
    for (int m = 1; m < 64; m <<= 1) { s += __shfl_xor(s, m); s2 += __shfl_xor(s2, m); }
    float mu  = s * (1.0f / HID);
    float var = s2 * (1.0f / HID) - mu * mu;
    float rstd = rsqrtf(var + 1e-5f);
    float o0 = fmaxf((v0 - mu) * rstd * ln_w[lane]      + ln_b[lane],      0.0f);
    float o1 = fmaxf((v1 - mu) * rstd * ln_w[lane + 64] + ln_b[lane + 64], 0.0f);
    h_out[(size_t)node * HID + lane]      = o0;
    h_out[(size_t)node * HID + lane + 64] = o1;
}

// ---------------- layers 1/2: [64 nodes] x (agg|h_in)[256] @ W[256][128] + LN + ReLU + res ----
// h_out may alias agg or h_in: each block stages its own 64 rows to LDS before writing.
template<int RES>
__global__ __launch_bounds__(256) void layer_kernel(
    const float* __restrict__ agg, const float* __restrict__ h_in,
    const float* __restrict__ w_l, const float* __restrict__ b_l, const float* __restrict__ w_r,
    const float* __restrict__ ln_w, const float* __restrict__ ln_b,
    float* __restrict__ h_out, int n)
{
    __shared__ float lds[64][260];   // [node][agg(128) | h_in(128)]
    int base = blockIdx.x * 64;
    int tid = threadIdx.x;
    #pragma unroll
    for (int i = 0; i < 8; ++i) {
        int idx = tid + i * 256;
        int row = idx >> 5;
        int c4  = (idx & 31) * 4;
        int node = base + row;
        float4 a = make_float4(0.f, 0.f, 0.f, 0.f);
        float4 h = make_float4(0.f, 0.f, 0.f, 0.f);
        if (node < n) {
            a = *(const float4*)(agg  + (size_t)node * HID + c4);
            h = *(const float4*)(h_in + (size_t)node * HID + c4);
        }
        *(float4*)&lds[row][c4]       = a;
        *(float4*)&lds[row][HID + c4] = h;
    }
    __syncthreads();

    int tx = tid & 31, ty = tid >> 5;
    float acc[8][4];
    #pragma unroll
    for (int r = 0; r < 8; ++r) { acc[r][0] = acc[r][1] = acc[r][2] = acc[r][3] = 0.f; }

    const float* W = w_l;
    #pragma unroll
    for (int half = 0; half < 2; ++half) {
        int koff = half * HID;
        for (int k = 0; k < HID; k += 4) {
            float4 w0 = *(const float4*)(W + (size_t)(k + 0) * HID + tx * 4);
            float4 w1 = *(const float4*)(W + (size_t)(k + 1) * HID + tx * 4);
            float4 w2 = *(const float4*)(W + (size_t)(k + 2) * HID + tx * 4);
            float4 w3 = *(const float4*)(W + (size_t)(k + 3) * HID + tx * 4);
            #pragma unroll
            for (int r = 0; r < 8; ++r) {
                float4 a = *(const float4*)&lds[ty * 8 + r][koff + k];
                acc[r][0] = fmaf(a.x, w0.x, fmaf(a.y, w1.x, fmaf(a.z, w2.x, fmaf(a.w, w3.x, acc[r][0]))));
                acc[r][1] = fmaf(a.x, w0.y, fmaf(a.y, w1.y, fmaf(a.z, w2.y, fmaf(a.w, w3.y, acc[r][1]))));
                acc[r][2] = fmaf(a.x, w0.z, fmaf(a.y, w1.z, fmaf(a.z, w2.z, fmaf(a.w, w3.z, acc[r][2]))));
                acc[r][3] = fmaf(a.x, w0.w, fmaf(a.y, w1.w, fmaf(a.z, w2.w, fmaf(a.w, w3.w, acc[r][3]))));
            }
        }
        W = w_r;
    }

    float4 bl = *(const float4*)(b_l  + tx * 4);
    float4 gw = *(const float4*)(ln_w + tx * 4);
    float4 gb = *(const float4*)(ln_b + tx * 4);
    #pragma unroll
    for (int r = 0; r < 8; ++r) {
        float v0 = acc[r][0] + bl.x, v1 = acc[r][1] + bl.y;
        float v2 = acc[r][2] + bl.z, v3 = acc[r][3] + bl.w;
        float s  = v0 + v1 + v2 + v3;
        float s2 = v0*v0 + v1*v1 + v2*v2 + v3*v3;
        #pragma unroll
        for (int m = 16; m >= 1; m >>= 1) { s += __shfl_xor(s, m); s2 += __shfl_xor(s2, m); }
        float mu  = s * (1.0f / HID);
        float var = s2 * (1.0f / HID) - mu * mu;
        float rstd = rsqrtf(var + 1e-5f);
        int row = ty * 8 + r;
        float o0 = fmaxf((v0 - mu) * rstd * gw.x + gb.x, 0.f);
        float o1 = fmaxf((v1 - mu) * rstd * gw.y + gb.y, 0.f);
        float o2 = fmaxf((v2 - mu) * rstd * gw.z + gb.z, 0.f);
        float o3 = fmaxf((v3 - mu) * rstd * gw.w + gb.w, 0.f);
        if (RES) {
            o0 += lds[row][HID + tx * 4 + 0];
            o1 += lds[row][HID + tx * 4 + 1];
            o2 += lds[row][HID + tx * 4 + 2];
            o3 += lds[row][HID + tx * 4 + 3];
        }
        int node = base + row;
        if (node < n) {
            float4 o = make_float4(o0, o1, o2, o3);
            *(float4*)(h_out + (size_t)node * HID + tx * 4) = o;
        }
    }
}

// ---------------- classifier ----------------
__global__ __launch_bounds__(256) void cls_kernel(
    const float* __restrict__ h, const float* __restrict__ w0, const float* __restrict__ b0,
    const float* __restrict__ w1, const float* __restrict__ b1, float* __restrict__ out, int n)
{
    __shared__ float w0s[HID * 64];
    __shared__ float w1s[64];
    int tid = threadIdx.x;
    #pragma unroll
    for (int i = 0; i < 32; ++i) w0s[tid + i * 256] = w0[tid + i * 256];
    if (tid < 64) w1s[tid] = w1[tid];
    __syncthreads();
    int lane = tid & 63, wv = tid >> 6;
    float bb0 = b0[lane], bb1 = b1[0];
    for (int i = 0; i < 16; ++i) {
        int node = blockIdx.x * 64 + wv * 16 + i;
        if (node >= n) break;
        const float* hr = h + (size_t)node * HID;
        float s = bb0;
        #pragma unroll 4
        for (int k = 0; k < HID; k += 4) {
            float4 hv = *(const float4*)(hr + k);
            s = fmaf(hv.x, w0s[(k + 0) * 64 + lane], s);
            s = fmaf(hv.y, w0s[(k + 1) * 64 + lane], s);
            s = fmaf(hv.z, w0s[(k + 2) * 64 + lane], s);
            s = fmaf(hv.w, w0s[(k + 3) * 64 + lane], s);
        }
        s = fmaxf(s, 0.f);
        float t = s * w1s[lane];
        #pragma unroll
        for (int m = 1; m < 64; m <<= 1) t += __shfl_xor(t, m);
        if (lane == 0) out[node] = t + bb1;
    }
}

extern "C" void kernel_launch(void* const* d_in, const int* in_sizes, int n_in,
                              void* d_out, int out_size, void* d_ws, size_t ws_size,
                              hipStream_t stream) {
    const float* x  = (const float*)d_in[0];
    const int*   ei = (const int*)d_in[1];     // integer inputs arrive as int32
    const float* w_l0 = (const float*)d_in[2];
    const float* b_l0 = (const float*)d_in[3];
    const float* w_r0 = (const float*)d_in[4];
    const float* lnw0 = (const float*)d_in[5];
    const float* lnb0 = (const float*)d_in[6];
    const float* w_l1 = (const float*)d_in[7];
    const float* b_l1 = (const float*)d_in[8];
    const float* w_r1 = (const float*)d_in[9];
    const float* lnw1 = (const float*)d_in[10];
    const float* lnb1 = (const float*)d_in[11];
    const float* w_l2 = (const float*)d_in[12];
    const float* b_l2 = (const float*)d_in[13];
    const float* w_r2 = (const float*)d_in[14];
    const float* lnw2 = (const float*)d_in[15];
    const float* lnb2 = (const float*)d_in[16];
    const float* c_w0 = (const float*)d_in[17];
    const float* c_b0 = (const float*)d_in[18];
    const float* c_w1 = (const float*)d_in[19];
    const float* c_b1 = (const float*)d_in[20];
    float* out = (float*)d_out;

    int N = in_sizes[0] / 11;
    int E = in_sizes[1] / 2;
    int nb = (N + 255) / 256;      // scan blocks (196 for N=50000)

    // workspace (ints then floats):
    // [deg: N][rp: N+1][cursor: N][csr_src: E][part: nb]  [bufA: N*HID][bufB: N*HID]
    int*   deg    = (int*)d_ws;
    int*   rp     = deg + N;
    int*   cursor = rp + (N + 1);
    int*   csr    = cursor + N;
    int*   part   = csr + E;
    float* bufA   = (float*)(part + ((nb + 63) & ~63));
    float* bufB   = bufA + (size_t)N * HID;

    // ---- CSR build (once, reused by all 3 layers) ----
    hipMemsetAsync(deg, 0, (size_t)N * sizeof(int), stream);
    deg_kernel<<<(E + 255) / 256, 256, 0, stream>>>(ei, deg, E);
    part_kernel<<<nb, 256, 0, stream>>>(deg, part, N);
    scanpart_kernel<<<1, 1024, 0, stream>>>(part, nb);
    rp_kernel<<<nb, 256, 0, stream>>>(deg, part, rp, cursor, N);
    fill_kernel<<<(E + 255) / 256, 256, 0, stream>>>(ei, cursor, csr, E);

    int nodeBlocks = (N + 3) / 4;   // 4 waves of node-work per 256-thread block

    // ---- layer 0 ----  h0 -> bufA
    layer0_kernel<<<nodeBlocks, 256, 0, stream>>>(x, rp, csr, w_l0, b_l0, w_r0, lnw0, lnb0, bufA, N);

    // ---- layer 1 ----  agg(bufA)->bufB ; layer(bufB, bufA) -> bufA (alias-safe: LDS staged)
    aggp_kernel<<<nodeBlocks, 256, 0, stream>>>(rp, csr, bufA, bufB, N);
    layer_kernel<1><<<(N + 63) / 64, 256, 0, stream>>>(bufB, bufA, w_l1, b_l1, w_r1, lnw1, lnb1, bufA, N);

    // ---- layer 2 ----  agg(bufA)->bufB ; layer(bufB, bufA) -> bufA
    aggp_kernel<<<nodeBlocks, 256, 0, stream>>>(rp, csr, bufA, bufB, N);
    layer_kernel<1><<<(N + 63) / 64, 256, 0, stream>>>(bufB, bufA, w_l2, b_l2, w_r2, lnw2, lnb2, bufA, N);

    // ---- classifier ----
    cls_kernel<<<(N + 63) / 64, 256, 0, stream>>>(bufA, c_w0, c_b0, c_w1, c_b1, out, N);
}

// Round 5
// 462.533 us; speedup vs baseline: 3.5774x; 1.0096x over previous
//
#include <hip/hip_runtime.h>

#define HID 128

// ---------------- degree histogram (int) ----------------
__global__ __launch_bounds__(256) void deg_kernel(const int* __restrict__ ei,
                                                  int* __restrict__ deg, int E) {
    int e = blockIdx.x * 256 + threadIdx.x;
    if (e >= E) return;
    atomicAdd(&deg[ei[E + e]], 1);
}

// ---------------- scan stage 1: per-block (256 elems) sums ----------------
__global__ __launch_bounds__(256) void part_kernel(const int* __restrict__ deg,
                                                   int* __restrict__ part, int n) {
    int i = blockIdx.x * 256 + threadIdx.x;
    int v = (i < n) ? deg[i] : 0;
    #pragma unroll
    for (int m = 1; m < 64; m <<= 1) v += __shfl_xor(v, m);
    __shared__ int w[4];
    int lane = threadIdx.x & 63, wv = threadIdx.x >> 6;
    if (lane == 0) w[wv] = v;
    __syncthreads();
    if (threadIdx.x == 0) part[blockIdx.x] = w[0] + w[1] + w[2] + w[3];
}

// ---------------- scan stage 2: exclusive scan of block sums ----------------
__global__ __launch_bounds__(1024) void scanpart_kernel(int* __restrict__ part, int nb) {
    __shared__ int s[1024];
    int t = threadIdx.x;
    int v = (t < nb) ? part[t] : 0;
    int orig = v;
    s[t] = v;
    __syncthreads();
    for (int off = 1; off < 1024; off <<= 1) {
        int u = (t >= off) ? s[t - off] : 0;
        __syncthreads();
        s[t] += u;
        __syncthreads();
    }
    if (t < nb) part[t] = s[t] - orig;   // exclusive
}

// ---------------- scan stage 3: per-block exclusive scan -> rp, cursor ----------------
__global__ __launch_bounds__(256) void rp_kernel(const int* __restrict__ deg,
                                                 const int* __restrict__ part,
                                                 int* __restrict__ rp,
                                                 int* __restrict__ cursor, int n) {
    int tid = threadIdx.x, lane = tid & 63, wv = tid >> 6;
    int i = blockIdx.x * 256 + tid;
    int v = (i < n) ? deg[i] : 0;
    int orig = v;
    #pragma unroll
    for (int off = 1; off < 64; off <<= 1) {
        int t = __shfl_up(v, off);
        if (lane >= off) v += t;
    }
    __shared__ int wsum[4];
    if (lane == 63) wsum[wv] = v;
    __syncthreads();
    int wbase = 0;
    #pragma unroll
    for (int w = 0; w < 4; ++w) if (w < wv) wbase += wsum[w];
    int excl = part[blockIdx.x] + wbase + v - orig;
    if (i < n) { rp[i] = excl; cursor[i] = excl; }
    if (i == n - 1) rp[n] = excl + orig;
}

// ---------------- CSR fill ----------------
__global__ __launch_bounds__(256) void fill_kernel(const int* __restrict__ ei,
                                                   int* __restrict__ cursor,
                                                   int* __restrict__ csr_src, int E) {
    int e = blockIdx.x * 256 + threadIdx.x;
    if (e >= E) return;
    int dst = ei[E + e];
    int pos = atomicAdd(&cursor[dst], 1);
    csr_src[pos] = ei[e];
}

// ---------------- 128-dim pull aggregation: one wave per node, writes MEAN ----------------
__global__ __launch_bounds__(256) void aggp_kernel(const int* __restrict__ rp,
                                                   const int* __restrict__ ci,
                                                   const float* __restrict__ h,
                                                   float* __restrict__ agg, int n) {
    int node = (blockIdx.x * 256 + threadIdx.x) >> 6;
    if (node >= n) return;
    int lane = threadIdx.x & 63;
    float2 a0 = make_float2(0.f, 0.f), a1 = make_float2(0.f, 0.f);
    float2 a2 = make_float2(0.f, 0.f), a3 = make_float2(0.f, 0.f);
    float2 a4 = make_float2(0.f, 0.f), a5 = make_float2(0.f, 0.f);
    float2 a6 = make_float2(0.f, 0.f), a7 = make_float2(0.f, 0.f);
    int beg = rp[node], end = rp[node + 1];
    int j = beg;
    for (; j + 7 < end; j += 8) {
        int s0 = ci[j],     s1 = ci[j + 1], s2 = ci[j + 2], s3 = ci[j + 3];
        int s4 = ci[j + 4], s5 = ci[j + 5], s6 = ci[j + 6], s7 = ci[j + 7];
        float2 v0 = *(const float2*)(h + (size_t)s0 * HID + lane * 2);
        float2 v1 = *(const float2*)(h + (size_t)s1 * HID + lane * 2);
        float2 v2 = *(const float2*)(h + (size_t)s2 * HID + lane * 2);
        float2 v3 = *(const float2*)(h + (size_t)s3 * HID + lane * 2);
        float2 v4 = *(const float2*)(h + (size_t)s4 * HID + lane * 2);
        float2 v5 = *(const float2*)(h + (size_t)s5 * HID + lane * 2);
        float2 v6 = *(const float2*)(h + (size_t)s6 * HID + lane * 2);
        float2 v7 = *(const float2*)(h + (size_t)s7 * HID + lane * 2);
        a0.x += v0.x; a0.y += v0.y;  a1.x += v1.x; a1.y += v1.y;
        a2.x += v2.x; a2.y += v2.y;  a3.x += v3.x; a3.y += v3.y;
        a4.x += v4.x; a4.y += v4.y;  a5.x += v5.x; a5.y += v5.y;
        a6.x += v6.x; a6.y += v6.y;  a7.x += v7.x; a7.y += v7.y;
    }
    for (; j + 3 < end; j += 4) {
        int s0 = ci[j], s1 = ci[j + 1], s2 = ci[j + 2], s3 = ci[j + 3];
        float2 v0 = *(const float2*)(h + (size_t)s0 * HID + lane * 2);
        float2 v1 = *(const float2*)(h + (size_t)s1 * HID + lane * 2);
        float2 v2 = *(const float2*)(h + (size_t)s2 * HID + lane * 2);
        float2 v3 = *(const float2*)(h + (size_t)s3 * HID + lane * 2);
        a0.x += v0.x; a0.y += v0.y;  a1.x += v1.x; a1.y += v1.y;
        a2.x += v2.x; a2.y += v2.y;  a3.x += v3.x; a3.y += v3.y;
    }
    for (; j < end; ++j) {
        int s0 = ci[j];
        float2 v0 = *(const float2*)(h + (size_t)s0 * HID + lane * 2);
        a0.x += v0.x; a0.y += v0.y;
    }
    float inv = 1.0f / fmaxf((float)(end - beg), 1.0f);
    float2 o = make_float2((a0.x + a1.x + a2.x + a3.x + a4.x + a5.x + a6.x + a7.x) * inv,
                           (a0.y + a1.y + a2.y + a3.y + a4.y + a5.y + a6.y + a7.y) * inv);
    *(float2*)(agg + (size_t)node * HID + lane * 2) = o;
}

// ---------------- layer 0: fused 11-dim pull-agg + dual matmul + LN + ReLU ----------------
// Gather: 5 neighbors/round across 55 lanes (lane = g*11 + d), then shfl-fold the 5 groups.
__global__ __launch_bounds__(256) void layer0_kernel(
    const float* __restrict__ x, const int* __restrict__ rp, const int* __restrict__ ci,
    const float* __restrict__ w_l, const float* __restrict__ b_l, const float* __restrict__ w_r,
    const float* __restrict__ ln_w, const float* __restrict__ ln_b,
    float* __restrict__ h_out, int n)
{
    int node = (blockIdx.x * 256 + threadIdx.x) >> 6;
    int lane = threadIdx.x & 63;
    if (node >= n) return;
    int beg = rp[node], end = rp[node + 1];
    // parallel gather: group g = lane/11 (0..4 valid), dim d = lane - g*11
    int g = lane / 11;           // lanes 55..63 -> g=5 (idle)
    int d = lane - g * 11;
    float acc0 = 0.f, acc1 = 0.f;
    int j = beg + g;
    if (g < 5) {
        for (; j + 5 < end; j += 10) {
            int s0 = ci[j], s1 = ci[j + 5];
            acc0 += x[(size_t)s0 * 11 + d];
            acc1 += x[(size_t)s1 * 11 + d];
        }
        for (; j < end; j += 5) {
            int s0 = ci[j];
            acc0 += x[(size_t)s0 * 11 + d];
        }
    }
    float acc = acc0 + acc1;
    // fold groups: lane l (0..10) sums lanes l, l+11, l+22, l+33, l+44
    float aggk = 0.f;
    #pragma unroll
    for (int gg = 0; gg < 5; ++gg) {
        float v = __shfl(acc, lane + 11 * gg >= 64 ? lane : lane + 11 * gg);
        // guard: only meaningful for lane<11; compute real source below
        aggk += __shfl(acc, (lane < 11) ? (lane + 11 * gg) : lane);
        (void)v;
    }
    float inv = 1.0f / fmaxf((float)(end - beg), 1.0f);
    float v0 = b_l[lane], v1 = b_l[lane + 64];
    #pragma unroll
    for (int k = 0; k < 11; ++k) {
        float a  = __shfl(aggk, k) * inv;
        float xi = x[(size_t)node * 11 + k];
        v0 += a * w_l[k * HID + lane]      + xi * w_r[k * HID + lane];
        v1 += a * w_l[k * HID + lane + 64] + xi * w_r[k * HID + lane + 64];
    }
    float s = v0 + v1, s2 = v0 * v0 + v1 * v1;
    #pragma unroll
    for (int m = 1; m < 64; m <<= 1) { s += __shfl_xor(s, m); s2 += __shfl_xor(s2, m); }
    float mu  = s * (1.0f / HID);
    float var = s2 * (1.0f / HID) - mu * mu;
    float rstd = rsqrtf(var + 1e-5f);
    float o0 = fmaxf((v0 - mu) * rstd * ln_w[lane]      + ln_b[lane],      0.0f);
    float o1 = fmaxf((v1 - mu) * rstd * ln_w[lane + 64] + ln_b[lane + 64], 0.0f);
    h_out[(size_t)node * HID + lane]      = o0;
    h_out[(size_t)node * HID + lane + 64] = o1;
}

// ---------------- layers 1/2: 512 threads, 64 nodes x (agg|h_in)[256] @ W + LN + ReLU + res ----
// CLS=1: additionally computes classifier from LDS-resident h and writes out[]; skips h_out.
// h_out may alias agg or h_in: block stages its 64 rows to LDS before any write.
template<int RES, int CLS>
__global__ __launch_bounds__(512) void layer_kernel(
    const float* __restrict__ agg, const float* __restrict__ h_in,
    const float* __restrict__ w_l, const float* __restrict__ b_l, const float* __restrict__ w_r,
    const float* __restrict__ ln_w, const float* __restrict__ ln_b,
    float* __restrict__ h_out,
    const float* __restrict__ c_w0, const float* __restrict__ c_b0,
    const float* __restrict__ c_w1, const float* __restrict__ c_b1,
    float* __restrict__ cls_out, int n)
{
    __shared__ float lds[64][260];   // [node][agg(128) | h_in(128)]
    int base = blockIdx.x * 64;
    int tid = threadIdx.x;
    #pragma unroll
    for (int i = 0; i < 4; ++i) {
        int idx = tid + i * 512;
        int row = idx >> 5;
        int c4  = (idx & 31) * 4;
        int node = base + row;
        float4 a = make_float4(0.f, 0.f, 0.f, 0.f);
        float4 h = make_float4(0.f, 0.f, 0.f, 0.f);
        if (node < n) {
            a = *(const float4*)(agg  + (size_t)node * HID + c4);
            h = *(const float4*)(h_in + (size_t)node * HID + c4);
        }
        *(float4*)&lds[row][c4]       = a;
        *(float4*)&lds[row][HID + c4] = h;
    }
    __syncthreads();

    int tx = tid & 31, ty = tid >> 5;   // tx: 32 col-groups (4 cols), ty: 16 row-groups (4 rows)
    float acc[4][4];
    #pragma unroll
    for (int r = 0; r < 4; ++r) { acc[r][0] = acc[r][1] = acc[r][2] = acc[r][3] = 0.f; }

    const float* W = w_l;
    #pragma unroll
    for (int half = 0; half < 2; ++half) {
        int koff = half * HID;
        for (int k = 0; k < HID; k += 4) {
            float4 w0 = *(const float4*)(W + (size_t)(k + 0) * HID + tx * 4);
            float4 w1 = *(const float4*)(W + (size_t)(k + 1) * HID + tx * 4);
            float4 w2 = *(const float4*)(W + (size_t)(k + 2) * HID + tx * 4);
            float4 w3 = *(const float4*)(W + (size_t)(k + 3) * HID + tx * 4);
            #pragma unroll
            for (int r = 0; r < 4; ++r) {
                float4 a = *(const float4*)&lds[ty * 4 + r][koff + k];
                acc[r][0] = fmaf(a.x, w0.x, fmaf(a.y, w1.x, fmaf(a.z, w2.x, fmaf(a.w, w3.x, acc[r][0]))));
                acc[r][1] = fmaf(a.x, w0.y, fmaf(a.y, w1.y, fmaf(a.z, w2.y, fmaf(a.w, w3.y, acc[r][1]))));
                acc[r][2] = fmaf(a.x, w0.z, fmaf(a.y, w1.z, fmaf(a.z, w2.z, fmaf(a.w, w3.z, acc[r][2]))));
                acc[r][3] = fmaf(a.x, w0.w, fmaf(a.y, w1.w, fmaf(a.z, w2.w, fmaf(a.w, w3.w, acc[r][3]))));
            }
        }
        W = w_r;
    }

    if (CLS) __syncthreads();   // about to overwrite the agg half of lds

    float4 bl = *(const float4*)(b_l  + tx * 4);
    float4 gw = *(const float4*)(ln_w + tx * 4);
    float4 gb = *(const float4*)(ln_b + tx * 4);
    #pragma unroll
    for (int r = 0; r < 4; ++r) {
        float v0 = acc[r][0] + bl.x, v1 = acc[r][1] + bl.y;
        float v2 = acc[r][2] + bl.z, v3 = acc[r][3] + bl.w;
        float s  = v0 + v1 + v2 + v3;
        float s2 = v0*v0 + v1*v1 + v2*v2 + v3*v3;
        #pragma unroll
        for (int m = 16; m >= 1; m >>= 1) { s += __shfl_xor(s, m); s2 += __shfl_xor(s2, m); }
        float mu  = s * (1.0f / HID);
        float var = s2 * (1.0f / HID) - mu * mu;
        float rstd = rsqrtf(var + 1e-5f);
        int row = ty * 4 + r;
        float o0 = fmaxf((v0 - mu) * rstd * gw.x + gb.x, 0.f);
        float o1 = fmaxf((v1 - mu) * rstd * gw.y + gb.y, 0.f);
        float o2 = fmaxf((v2 - mu) * rstd * gw.z + gb.z, 0.f);
        float o3 = fmaxf((v3 - mu) * rstd * gw.w + gb.w, 0.f);
        if (RES) {
            o0 += lds[row][HID + tx * 4 + 0];
            o1 += lds[row][HID + tx * 4 + 1];
            o2 += lds[row][HID + tx * 4 + 2];
            o3 += lds[row][HID + tx * 4 + 3];
        }
        int node = base + row;
        if (CLS) {
            *(float4*)&lds[row][tx * 4] = make_float4(o0, o1, o2, o3);
        } else if (node < n) {
            *(float4*)(h_out + (size_t)node * HID + tx * 4) = make_float4(o0, o1, o2, o3);
        }
    }

    if (CLS) {
        __syncthreads();
        int lane = tid & 63, wv = tid >> 6;   // 8 waves, 8 nodes each
        float bb0 = c_b0[lane], ww1 = c_w1[lane], bb1 = c_b1[0];
        #pragma unroll 1
        for (int q = 0; q < 8; ++q) {
            int row = wv * 8 + q;
            int node = base + row;
            if (node >= n) break;
            float s = bb0;
            #pragma unroll 4
            for (int k = 0; k < HID; k += 4) {
                float4 hv = *(const float4*)&lds[row][k];
                s = fmaf(hv.x, c_w0[(k + 0) * 64 + lane], s);
                s = fmaf(hv.y, c_w0[(k + 1) * 64 + lane], s);
                s = fmaf(hv.z, c_w0[(k + 2) * 64 + lane], s);
                s = fmaf(hv.w, c_w0[(k + 3) * 64 + lane], s);
            }
            s = fmaxf(s, 0.f);
            float t = s * ww1;
            #pragma unroll
            for (int m = 1; m < 64; m <<= 1) t += __shfl_xor(t, m);
            if (lane == 0) cls_out[node] = t + bb1;
        }
    }
}

extern "C" void kernel_launch(void* const* d_in, const int* in_sizes, int n_in,
                              void* d_out, int out_size, void* d_ws, size_t ws_size,
                              hipStream_t stream) {
    const float* x  = (const float*)d_in[0];
    const int*   ei = (const int*)d_in[1];     // integer inputs arrive as int32
    const float* w_l0 = (const float*)d_in[2];
    const float* b_l0 = (const float*)d_in[3];
    const float* w_r0 = (const float*)d_in[4];
    const float* lnw0 = (const float*)d_in[5];
    const float* lnb0 = (const float*)d_in[6];
    const float* w_l1 = (const float*)d_in[7];
    const float* b_l1 = (const float*)d_in[8];
    const float* w_r1 = (const float*)d_in[9];
    const float* lnw1 = (const float*)d_in[10];
    const float* lnb1 = (const float*)d_in[11];
    const float* w_l2 = (const float*)d_in[12];
    const float* b_l2 = (const float*)d_in[13];
    const float* w_r2 = (const float*)d_in[14];
    const float* lnw2 = (const float*)d_in[15];
    const float* lnb2 = (const float*)d_in[16];
    const float* c_w0 = (const float*)d_in[17];
    const float* c_b0 = (const float*)d_in[18];
    const float* c_w1 = (const float*)d_in[19];
    const float* c_b1 = (const float*)d_in[20];
    float* out = (float*)d_out;

    int N = in_sizes[0] / 11;
    int E = in_sizes[1] / 2;
    int nb = (N + 255) / 256;

    // workspace: [deg: N][rp: N+1][cursor: N][csr: E][part: nb] [bufA: N*HID][bufB: N*HID]
    int*   deg    = (int*)d_ws;
    int*   rp     = deg + N;
    int*   cursor = rp + (N + 1);
    int*   csr    = cursor + N;
    int*   part   = csr + E;
    float* bufA   = (float*)(part + ((nb + 63) & ~63));
    float* bufB   = bufA + (size_t)N * HID;

    // ---- CSR build ----
    hipMemsetAsync(deg, 0, (size_t)N * sizeof(int), stream);
    deg_kernel<<<(E + 255) / 256, 256, 0, stream>>>(ei, deg, E);
    part_kernel<<<nb, 256, 0, stream>>>(deg, part, N);
    scanpart_kernel<<<1, 1024, 0, stream>>>(part, nb);
    rp_kernel<<<nb, 256, 0, stream>>>(deg, part, rp, cursor, N);
    fill_kernel<<<(E + 255) / 256, 256, 0, stream>>>(ei, cursor, csr, E);

    int nodeBlocks = (N + 3) / 4;

    // ---- layer 0 ----
    layer0_kernel<<<nodeBlocks, 256, 0, stream>>>(x, rp, csr, w_l0, b_l0, w_r0, lnw0, lnb0, bufA, N);

    // ---- layer 1 ----
    aggp_kernel<<<nodeBlocks, 256, 0, stream>>>(rp, csr, bufA, bufB, N);
    layer_kernel<1, 0><<<(N + 63) / 64, 512, 0, stream>>>(bufB, bufA, w_l1, b_l1, w_r1, lnw1, lnb1,
                                                          bufA, nullptr, nullptr, nullptr, nullptr, nullptr, N);

    // ---- layer 2 + fused classifier ----
    aggp_kernel<<<nodeBlocks, 256, 0, stream>>>(rp, csr, bufA, bufB, N);
    layer_kernel<1, 1><<<(N + 63) / 64, 512, 0, stream>>>(bufB, bufA, w_l2, b_l2, w_r2, lnw2, lnb2,
                                                          nullptr, c_w0, c_b0, c_w1, c_b1, out, N);
}

// Round 6
// 445.740 us; speedup vs baseline: 3.7122x; 1.0377x over previous
//
#include <hip/hip_runtime.h>

#define HID 128

// ---------------- degree histogram (int) ----------------
__global__ __launch_bounds__(256) void deg_kernel(const int* __restrict__ ei,
                                                  int* __restrict__ deg, int E) {
    int e = blockIdx.x * 256 + threadIdx.x;
    if (e >= E) return;
    atomicAdd(&deg[ei[E + e]], 1);
}

// ---------------- scan stage 1: per-block (256 elems) sums ----------------
__global__ __launch_bounds__(256) void part_kernel(const int* __restrict__ deg,
                                                   int* __restrict__ part, int n) {
    int i = blockIdx.x * 256 + threadIdx.x;
    int v = (i < n) ? deg[i] : 0;
    #pragma unroll
    for (int m = 1; m < 64; m <<= 1) v += __shfl_xor(v, m);
    __shared__ int w[4];
    int lane = threadIdx.x & 63, wv = threadIdx.x >> 6;
    if (lane == 0) w[wv] = v;
    __syncthreads();
    if (threadIdx.x == 0) part[blockIdx.x] = w[0] + w[1] + w[2] + w[3];
}

// ---------------- scan stage 2: exclusive scan of block sums ----------------
__global__ __launch_bounds__(1024) void scanpart_kernel(int* __restrict__ part, int nb) {
    __shared__ int s[1024];
    int t = threadIdx.x;
    int v = (t < nb) ? part[t] : 0;
    int orig = v;
    s[t] = v;
    __syncthreads();
    for (int off = 1; off < 1024; off <<= 1) {
        int u = (t >= off) ? s[t - off] : 0;
        __syncthreads();
        s[t] += u;
        __syncthreads();
    }
    if (t < nb) part[t] = s[t] - orig;   // exclusive
}

// ---------------- scan stage 3: per-block exclusive scan -> rp, cursor ----------------
__global__ __launch_bounds__(256) void rp_kernel(const int* __restrict__ deg,
                                                 const int* __restrict__ part,
                                                 int* __restrict__ rp,
                                                 int* __restrict__ cursor, int n) {
    int tid = threadIdx.x, lane = tid & 63, wv = tid >> 6;
    int i = blockIdx.x * 256 + tid;
    int v = (i < n) ? deg[i] : 0;
    int orig = v;
    #pragma unroll
    for (int off = 1; off < 64; off <<= 1) {
        int t = __shfl_up(v, off);
        if (lane >= off) v += t;
    }
    __shared__ int wsum[4];
    if (lane == 63) wsum[wv] = v;
    __syncthreads();
    int wbase = 0;
    #pragma unroll
    for (int w = 0; w < 4; ++w) if (w < wv) wbase += wsum[w];
    int excl = part[blockIdx.x] + wbase + v - orig;
    if (i < n) { rp[i] = excl; cursor[i] = excl; }
    if (i == n - 1) rp[n] = excl + orig;
}

// ---------------- CSR fill ----------------
__global__ __launch_bounds__(256) void fill_kernel(const int* __restrict__ ei,
                                                   int* __restrict__ cursor,
                                                   int* __restrict__ csr_src, int E) {
    int e = blockIdx.x * 256 + threadIdx.x;
    if (e >= E) return;
    int dst = ei[E + e];
    int pos = atomicAdd(&cursor[dst], 1);
    csr_src[pos] = ei[e];
}

// ---------------- 128-dim pull aggregation: one wave per node, writes MEAN ----------------
__global__ __launch_bounds__(256) void aggp_kernel(const int* __restrict__ rp,
                                                   const int* __restrict__ ci,
                                                   const float* __restrict__ h,
                                                   float* __restrict__ agg, int n) {
    int node = (blockIdx.x * 256 + threadIdx.x) >> 6;
    if (node >= n) return;
    int lane = threadIdx.x & 63;
    float2 a0 = make_float2(0.f, 0.f), a1 = make_float2(0.f, 0.f);
    float2 a2 = make_float2(0.f, 0.f), a3 = make_float2(0.f, 0.f);
    float2 a4 = make_float2(0.f, 0.f), a5 = make_float2(0.f, 0.f);
    float2 a6 = make_float2(0.f, 0.f), a7 = make_float2(0.f, 0.f);
    int beg = rp[node], end = rp[node + 1];
    int j = beg;
    for (; j + 7 < end; j += 8) {
        int s0 = ci[j],     s1 = ci[j + 1], s2 = ci[j + 2], s3 = ci[j + 3];
        int s4 = ci[j + 4], s5 = ci[j + 5], s6 = ci[j + 6], s7 = ci[j + 7];
        float2 v0 = *(const float2*)(h + (size_t)s0 * HID + lane * 2);
        float2 v1 = *(const float2*)(h + (size_t)s1 * HID + lane * 2);
        float2 v2 = *(const float2*)(h + (size_t)s2 * HID + lane * 2);
        float2 v3 = *(const float2*)(h + (size_t)s3 * HID + lane * 2);
        float2 v4 = *(const float2*)(h + (size_t)s4 * HID + lane * 2);
        float2 v5 = *(const float2*)(h + (size_t)s5 * HID + lane * 2);
        float2 v6 = *(const float2*)(h + (size_t)s6 * HID + lane * 2);
        float2 v7 = *(const float2*)(h + (size_t)s7 * HID + lane * 2);
        a0.x += v0.x; a0.y += v0.y;  a1.x += v1.x; a1.y += v1.y;
        a2.x += v2.x; a2.y += v2.y;  a3.x += v3.x; a3.y += v3.y;
        a4.x += v4.x; a4.y += v4.y;  a5.x += v5.x; a5.y += v5.y;
        a6.x += v6.x; a6.y += v6.y;  a7.x += v7.x; a7.y += v7.y;
    }
    for (; j + 3 < end; j += 4) {
        int s0 = ci[j], s1 = ci[j + 1], s2 = ci[j + 2], s3 = ci[j + 3];
        float2 v0 = *(const float2*)(h + (size_t)s0 * HID + lane * 2);
        float2 v1 = *(const float2*)(h + (size_t)s1 * HID + lane * 2);
        float2 v2 = *(const float2*)(h + (size_t)s2 * HID + lane * 2);
        float2 v3 = *(const float2*)(h + (size_t)s3 * HID + lane * 2);
        a0.x += v0.x; a0.y += v0.y;  a1.x += v1.x; a1.y += v1.y;
        a2.x += v2.x; a2.y += v2.y;  a3.x += v3.x; a3.y += v3.y;
    }
    for (; j < end; ++j) {
        int s0 = ci[j];
        float2 v0 = *(const float2*)(h + (size_t)s0 * HID + lane * 2);
        a0.x += v0.x; a0.y += v0.y;
    }
    float inv = 1.0f / fmaxf((float)(end - beg), 1.0f);
    float2 o = make_float2((a0.x + a1.x + a2.x + a3.x + a4.x + a5.x + a6.x + a7.x) * inv,
                           (a0.y + a1.y + a2.y + a3.y + a4.y + a5.y + a6.y + a7.y) * inv);
    *(float2*)(agg + (size_t)node * HID + lane * 2) = o;
}

// ---------------- layer 0: fused 11-dim pull-agg + dual matmul + LN + ReLU ----------------
__global__ __launch_bounds__(256) void layer0_kernel(
    const float* __restrict__ x, const int* __restrict__ rp, const int* __restrict__ ci,
    const float* __restrict__ w_l, const float* __restrict__ b_l, const float* __restrict__ w_r,
    const float* __restrict__ ln_w, const float* __restrict__ ln_b,
    float* __restrict__ h_out, int n)
{
    int node = (blockIdx.x * 256 + threadIdx.x) >> 6;
    int lane = threadIdx.x & 63;
    if (node >= n) return;
    int beg = rp[node], end = rp[node + 1];
    // parallel gather: group g = lane/11 (0..4 valid), dim d = lane - g*11
    int g = lane / 11;
    int d = lane - g * 11;
    float acc0 = 0.f, acc1 = 0.f;
    int j = beg + g;
    if (g < 5) {
        for (; j + 5 < end; j += 10) {
            int s0 = ci[j], s1 = ci[j + 5];
            acc0 += x[(size_t)s0 * 11 + d];
            acc1 += x[(size_t)s1 * 11 + d];
        }
        for (; j < end; j += 5) {
            int s0 = ci[j];
            acc0 += x[(size_t)s0 * 11 + d];
        }
    }
    float acc = acc0 + acc1;
    // fold: lane l (<11) sums lanes l, l+11, l+22, l+33, l+44
    float aggk = 0.f;
    #pragma unroll
    for (int gg = 0; gg < 5; ++gg) {
        aggk += __shfl(acc, (lane < 11) ? (lane + 11 * gg) : lane);
    }
    float inv = 1.0f / fmaxf((float)(end - beg), 1.0f);
    float v0 = b_l[lane], v1 = b_l[lane + 64];
    #pragma unroll
    for (int k = 0; k < 11; ++k) {
        float a  = __shfl(aggk, k) * inv;
        float xi = x[(size_t)node * 11 + k];
        v0 += a * w_l[k * HID + lane]      + xi * w_r[k * HID + lane];
        v1 += a * w_l[k * HID + lane + 64] + xi * w_r[k * HID + lane + 64];
    }
    float s = v0 + v1, s2 = v0 * v0 + v1 * v1;
    #pragma unroll
    for (int m = 1; m < 64; m <<= 1) { s += __shfl_xor(s, m); s2 += __shfl_xor(s2, m); }
    float mu  = s * (1.0f / HID);
    float var = s2 * (1.0f / HID) - mu * mu;
    float rstd = rsqrtf(var + 1e-5f);
    float o0 = fmaxf((v0 - mu) * rstd * ln_w[lane]      + ln_b[lane],      0.0f);
    float o1 = fmaxf((v1 - mu) * rstd * ln_w[lane + 64] + ln_b[lane + 64], 0.0f);
    h_out[(size_t)node * HID + lane]      = o0;
    h_out[(size_t)node * HID + lane + 64] = o1;
}

// ---------------- layers 1/2: K-split GEMM ----------------
// 256 threads = 2 K-halves x 4 row-groups(16 rows) x 32 col-groups(4 cols).
// khalf0 handles K 0..127 (w_l, agg half of LDS); khalf1 K 128..255 (w_r, h_in half).
// khalf1 dumps partials into the agg half of LDS; khalf0 combines + LN + ReLU + residual.
// h_out may alias agg or h_in: block stages its 64 rows to LDS before any global write.
template<int RES, int CLS>
__global__ __launch_bounds__(256) void layer_kernel(
    const float* __restrict__ agg, const float* __restrict__ h_in,
    const float* __restrict__ w_l, const float* __restrict__ b_l, const float* __restrict__ w_r,
    const float* __restrict__ ln_w, const float* __restrict__ ln_b,
    float* __restrict__ h_out,
    const float* __restrict__ c_w0, const float* __restrict__ c_b0,
    const float* __restrict__ c_w1, const float* __restrict__ c_b1,
    float* __restrict__ cls_out, int n)
{
    __shared__ float lds[64][260];   // [node][agg(128) | h_in(128)]
    int base = blockIdx.x * 64;
    int tid = threadIdx.x;
    #pragma unroll
    for (int i = 0; i < 8; ++i) {
        int idx = tid + i * 256;        // float4 index over 64*128/4 = 2048
        int row = idx >> 5;
        int c4  = (idx & 31) * 4;
        int node = base + row;
        float4 a = make_float4(0.f, 0.f, 0.f, 0.f);
        float4 h = make_float4(0.f, 0.f, 0.f, 0.f);
        if (node < n) {
            a = *(const float4*)(agg  + (size_t)node * HID + c4);
            h = *(const float4*)(h_in + (size_t)node * HID + c4);
        }
        *(float4*)&lds[row][c4]       = a;
        *(float4*)&lds[row][HID + c4] = h;
    }
    __syncthreads();

    int tx = tid & 31;            // 32 col-groups x 4 cols
    int ty = (tid >> 5) & 3;      // 4 row-groups x 16 rows
    int kh = tid >> 7;            // K half
    int koff = kh * HID;
    const float* W = kh ? w_r : w_l;

    float acc[16][4];
    #pragma unroll
    for (int r = 0; r < 16; ++r) { acc[r][0] = acc[r][1] = acc[r][2] = acc[r][3] = 0.f; }

    for (int k = 0; k < HID; k += 4) {
        float4 w0 = *(const float4*)(W + (size_t)(k + 0) * HID + tx * 4);
        float4 w1 = *(const float4*)(W + (size_t)(k + 1) * HID + tx * 4);
        float4 w2 = *(const float4*)(W + (size_t)(k + 2) * HID + tx * 4);
        float4 w3 = *(const float4*)(W + (size_t)(k + 3) * HID + tx * 4);
        #pragma unroll
        for (int r = 0; r < 16; ++r) {
            float4 a = *(const float4*)&lds[ty * 16 + r][koff + k];
            acc[r][0] = fmaf(a.x, w0.x, fmaf(a.y, w1.x, fmaf(a.z, w2.x, fmaf(a.w, w3.x, acc[r][0]))));
            acc[r][1] = fmaf(a.x, w0.y, fmaf(a.y, w1.y, fmaf(a.z, w2.y, fmaf(a.w, w3.y, acc[r][1]))));
            acc[r][2] = fmaf(a.x, w0.z, fmaf(a.y, w1.z, fmaf(a.z, w2.z, fmaf(a.w, w3.z, acc[r][2]))));
            acc[r][3] = fmaf(a.x, w0.w, fmaf(a.y, w1.w, fmaf(a.z, w2.w, fmaf(a.w, w3.w, acc[r][3]))));
        }
    }

    __syncthreads();   // all LDS compute reads done before partial dump

    if (kh == 1) {
        #pragma unroll
        for (int r = 0; r < 16; ++r) {
            *(float4*)&lds[ty * 16 + r][tx * 4] = make_float4(acc[r][0], acc[r][1], acc[r][2], acc[r][3]);
        }
    }
    __syncthreads();

    if (kh == 0) {
        float4 bl = *(const float4*)(b_l  + tx * 4);
        float4 gw = *(const float4*)(ln_w + tx * 4);
        float4 gb = *(const float4*)(ln_b + tx * 4);
        #pragma unroll
        for (int r = 0; r < 16; ++r) {
            int row = ty * 16 + r;
            float4 p = *(const float4*)&lds[row][tx * 4];
            float v0 = acc[r][0] + p.x + bl.x, v1 = acc[r][1] + p.y + bl.y;
            float v2 = acc[r][2] + p.z + bl.z, v3 = acc[r][3] + p.w + bl.w;
            float s  = v0 + v1 + v2 + v3;
            float s2 = v0*v0 + v1*v1 + v2*v2 + v3*v3;
            #pragma unroll
            for (int m = 16; m >= 1; m >>= 1) { s += __shfl_xor(s, m); s2 += __shfl_xor(s2, m); }
            float mu  = s * (1.0f / HID);
            float var = s2 * (1.0f / HID) - mu * mu;
            float rstd = rsqrtf(var + 1e-5f);
            float o0 = fmaxf((v0 - mu) * rstd * gw.x + gb.x, 0.f);
            float o1 = fmaxf((v1 - mu) * rstd * gw.y + gb.y, 0.f);
            float o2 = fmaxf((v2 - mu) * rstd * gw.z + gb.z, 0.f);
            float o3 = fmaxf((v3 - mu) * rstd * gw.w + gb.w, 0.f);
            if (RES) {
                o0 += lds[row][HID + tx * 4 + 0];
                o1 += lds[row][HID + tx * 4 + 1];
                o2 += lds[row][HID + tx * 4 + 2];
                o3 += lds[row][HID + tx * 4 + 3];
            }
            int node = base + row;
            if (CLS) {
                *(float4*)&lds[row][tx * 4] = make_float4(o0, o1, o2, o3);
            } else if (node < n) {
                *(float4*)(h_out + (size_t)node * HID + tx * 4) = make_float4(o0, o1, o2, o3);
            }
        }
    }

    if (CLS) {
        __syncthreads();
        int lane = tid & 63, wv = tid >> 6;   // 4 waves x 16 nodes
        float bb0 = c_b0[lane], ww1 = c_w1[lane], bb1 = c_b1[0];
        #pragma unroll 1
        for (int q = 0; q < 16; ++q) {
            int row = wv * 16 + q;
            int node = base + row;
            if (node >= n) break;
            float s = bb0;
            #pragma unroll 4
            for (int k = 0; k < HID; k += 4) {
                float4 hv = *(const float4*)&lds[row][k];
                s = fmaf(hv.x, c_w0[(k + 0) * 64 + lane], s);
                s = fmaf(hv.y, c_w0[(k + 1) * 64 + lane], s);
                s = fmaf(hv.z, c_w0[(k + 2) * 64 + lane], s);
                s = fmaf(hv.w, c_w0[(k + 3) * 64 + lane], s);
            }
            s = fmaxf(s, 0.f);
            float t = s * ww1;
            #pragma unroll
            for (int m = 1; m < 64; m <<= 1) t += __shfl_xor(t, m);
            if (lane == 0) cls_out[node] = t + bb1;
        }
    }
}

extern "C" void kernel_launch(void* const* d_in, const int* in_sizes, int n_in,
                              void* d_out, int out_size, void* d_ws, size_t ws_size,
                              hipStream_t stream) {
    const float* x  = (const float*)d_in[0];
    const int*   ei = (const int*)d_in[1];     // integer inputs arrive as int32
    const float* w_l0 = (const float*)d_in[2];
    const float* b_l0 = (const float*)d_in[3];
    const float* w_r0 = (const float*)d_in[4];
    const float* lnw0 = (const float*)d_in[5];
    const float* lnb0 = (const float*)d_in[6];
    const float* w_l1 = (const float*)d_in[7];
    const float* b_l1 = (const float*)d_in[8];
    const float* w_r1 = (const float*)d_in[9];
    const float* lnw1 = (const float*)d_in[10];
    const float* lnb1 = (const float*)d_in[11];
    const float* w_l2 = (const float*)d_in[12];
    const float* b_l2 = (const float*)d_in[13];
    const float* w_r2 = (const float*)d_in[14];
    const float* lnw2 = (const float*)d_in[15];
    const float* lnb2 = (const float*)d_in[16];
    const float* c_w0 = (const float*)d_in[17];
    const float* c_b0 = (const float*)d_in[18];
    const float* c_w1 = (const float*)d_in[19];
    const float* c_b1 = (const float*)d_in[20];
    float* out = (float*)d_out;

    int N = in_sizes[0] / 11;
    int E = in_sizes[1] / 2;
    int nb = (N + 255) / 256;

    // workspace: [deg: N][rp: N+1][cursor: N][csr: E][part: nb] [bufA: N*HID][bufB: N*HID]
    int*   deg    = (int*)d_ws;
    int*   rp     = deg + N;
    int*   cursor = rp + (N + 1);
    int*   csr    = cursor + N;
    int*   part   = csr + E;
    float* bufA   = (float*)(part + ((nb + 63) & ~63));
    float* bufB   = bufA + (size_t)N * HID;

    // ---- CSR build ----
    hipMemsetAsync(deg, 0, (size_t)N * sizeof(int), stream);
    deg_kernel<<<(E + 255) / 256, 256, 0, stream>>>(ei, deg, E);
    part_kernel<<<nb, 256, 0, stream>>>(deg, part, N);
    scanpart_kernel<<<1, 1024, 0, stream>>>(part, nb);
    rp_kernel<<<nb, 256, 0, stream>>>(deg, part, rp, cursor, N);
    fill_kernel<<<(E + 255) / 256, 256, 0, stream>>>(ei, cursor, csr, E);

    int nodeBlocks = (N + 3) / 4;

    // ---- layer 0 ----
    layer0_kernel<<<nodeBlocks, 256, 0, stream>>>(x, rp, csr, w_l0, b_l0, w_r0, lnw0, lnb0, bufA, N);

    // ---- layer 1 ----
    aggp_kernel<<<nodeBlocks, 256, 0, stream>>>(rp, csr, bufA, bufB, N);
    layer_kernel<1, 0><<<(N + 63) / 64, 256, 0, stream>>>(bufB, bufA, w_l1, b_l1, w_r1, lnw1, lnb1,
                                                          bufA, nullptr, nullptr, nullptr, nullptr, nullptr, N);

    // ---- layer 2 + fused classifier ----
    aggp_kernel<<<nodeBlocks, 256, 0, stream>>>(rp, csr, bufA, bufB, N);
    layer_kernel<1, 1><<<(N + 63) / 64, 256, 0, stream>>>(bufB, bufA, w_l2, b_l2, w_r2, lnw2, lnb2,
                                                          nullptr, c_w0, c_b0, c_w1, c_b1, out, N);
}